// Round 2
// baseline (169.932 us; speedup 1.0000x reference)
//
#include <hip/hip_runtime.h>

// rep config: E edges, D_IN = D_OUT = 4, M = 32 channels.
// out[e,o,m] = (sum_i basis[e,o,i] * nf[U[e],i,m]) * ew[e, (o==0?0:1), m]
//
// Mapping: 8 lanes per edge-pair channel-group; each thread owns a float4 of
// 4 channels for TWO consecutive edges (2x MLP, half the redundant U/basis
// issue). Single-use streams (basis, ew, out) use nontemporal hints so L2
// retains the gathered node_features table.

typedef float f4 __attribute__((ext_vector_type(4)));

__global__ __launch_bounds__(256) void equiv_mm_kernel(
    const float* __restrict__ basis,   // [E,4,4]
    const float* __restrict__ ew,      // [E,2,32]
    const float* __restrict__ nf,      // [N,4,32]
    const int*   __restrict__ U,       // [E]
    float*       __restrict__ out,     // [E,4,32]
    int E, int total)                  // total = (E/2)*8
{
    const int stride = gridDim.x * blockDim.x;
    for (int gid = blockIdx.x * blockDim.x + threadIdx.x; gid < total; gid += stride) {
        int p  = gid >> 3;            // edge-pair index
        int m0 = (gid & 7) << 2;      // channel offset: 0,4,...,28
        int e0 = p << 1;
        int e1 = e0 + 1;

        // both source indices in one 8B load
        int2 uu = ((const int2*)U)[p];

        // gather source-node features for both edges (8 outstanding loads)
        const f4* xp0 = (const f4*)(nf + (size_t)uu.x * 128 + m0);
        const f4* xp1 = (const f4*)(nf + (size_t)uu.y * 128 + m0);
        f4 a0 = xp0[0], a1 = xp0[8], a2 = xp0[16], a3 = xp0[24];
        f4 c0 = xp1[0], c1 = xp1[8], c2 = xp1[16], c3 = xp1[24];

        // per-edge 4x4 basis (single-use stream -> nontemporal)
        const f4* bp0 = (const f4*)(basis + (size_t)e0 * 16);
        f4 b00 = __builtin_nontemporal_load(bp0 + 0);
        f4 b01 = __builtin_nontemporal_load(bp0 + 1);
        f4 b02 = __builtin_nontemporal_load(bp0 + 2);
        f4 b03 = __builtin_nontemporal_load(bp0 + 3);
        f4 b10 = __builtin_nontemporal_load(bp0 + 4);
        f4 b11 = __builtin_nontemporal_load(bp0 + 5);
        f4 b12 = __builtin_nontemporal_load(bp0 + 6);
        f4 b13 = __builtin_nontemporal_load(bp0 + 7);

        // radial weights (single-use stream -> nontemporal)
        const f4* wp0 = (const f4*)(ew + (size_t)e0 * 64 + m0);
        f4 w00 = __builtin_nontemporal_load(wp0 + 0);
        f4 w01 = __builtin_nontemporal_load(wp0 + 8);
        f4 w10 = __builtin_nontemporal_load(wp0 + 16);
        f4 w11 = __builtin_nontemporal_load(wp0 + 24);

        // outputs (write-only stream -> nontemporal)
        f4* op0 = (f4*)(out + (size_t)e0 * 128 + m0);
        __builtin_nontemporal_store((b00.x*a0 + b00.y*a1 + b00.z*a2 + b00.w*a3) * w00, op0 + 0);
        __builtin_nontemporal_store((b01.x*a0 + b01.y*a1 + b01.z*a2 + b01.w*a3) * w01, op0 + 8);
        __builtin_nontemporal_store((b02.x*a0 + b02.y*a1 + b02.z*a2 + b02.w*a3) * w01, op0 + 16);
        __builtin_nontemporal_store((b03.x*a0 + b03.y*a1 + b03.z*a2 + b03.w*a3) * w01, op0 + 24);
        f4* op1 = (f4*)(out + (size_t)e1 * 128 + m0);
        __builtin_nontemporal_store((b10.x*c0 + b10.y*c1 + b10.z*c2 + b10.w*c3) * w10, op1 + 0);
        __builtin_nontemporal_store((b11.x*c0 + b11.y*c1 + b11.z*c2 + b11.w*c3) * w11, op1 + 8);
        __builtin_nontemporal_store((b12.x*c0 + b12.y*c1 + b12.z*c2 + b12.w*c3) * w11, op1 + 16);
        __builtin_nontemporal_store((b13.x*c0 + b13.y*c1 + b13.z*c2 + b13.w*c3) * w11, op1 + 24);
    }
}

// tail kernel for odd E (not hit with E=800000, but keep it correct)
__global__ void equiv_mm_tail(
    const float* __restrict__ basis, const float* __restrict__ ew,
    const float* __restrict__ nf, const int* __restrict__ U,
    float* __restrict__ out, int e)
{
    int m0 = (threadIdx.x & 7) << 2;
    int u = U[e];
    const f4* xp = (const f4*)(nf + (size_t)u * 128 + m0);
    f4 a0 = xp[0], a1 = xp[8], a2 = xp[16], a3 = xp[24];
    const f4* bp = (const f4*)(basis + (size_t)e * 16);
    f4 b0 = bp[0], b1 = bp[1], b2 = bp[2], b3 = bp[3];
    const f4* wp = (const f4*)(ew + (size_t)e * 64 + m0);
    f4 w0 = wp[0], w1 = wp[8];
    f4* op = (f4*)(out + (size_t)e * 128 + m0);
    op[0]  = (b0.x*a0 + b0.y*a1 + b0.z*a2 + b0.w*a3) * w0;
    op[8]  = (b1.x*a0 + b1.y*a1 + b1.z*a2 + b1.w*a3) * w1;
    op[16] = (b2.x*a0 + b2.y*a1 + b2.z*a2 + b2.w*a3) * w1;
    op[24] = (b3.x*a0 + b3.y*a1 + b3.z*a2 + b3.w*a3) * w1;
}

extern "C" void kernel_launch(void* const* d_in, const int* in_sizes, int n_in,
                              void* d_out, int out_size, void* d_ws, size_t ws_size,
                              hipStream_t stream) {
    const float* basis = (const float*)d_in[0];   // [E,4,4]
    const float* ew    = (const float*)d_in[1];   // [E,2,32]
    const float* nf    = (const float*)d_in[2];   // [N,4,32]
    const int*   U     = (const int*)d_in[3];     // [E]
    float* out = (float*)d_out;

    int E = in_sizes[0] / 16;
    int pairs = E >> 1;
    int total = pairs * 8;                 // 8 threads per edge-pair
    int block = 256;
    int grid = (total + block - 1) / block;
    if (grid > 2048) grid = 2048;          // grid-stride; fills 256 CU x 2048 thr

    equiv_mm_kernel<<<grid, block, 0, stream>>>(basis, ew, nf, U, out, E, total);
    if (E & 1)
        equiv_mm_tail<<<1, 8, 0, stream>>>(basis, ew, nf, U, out, E - 1);
}

// Round 3
// 151.950 us; speedup vs baseline: 1.1183x; 1.1183x over previous
//
#include <hip/hip_runtime.h>

// rep config: E edges, D_IN = D_OUT = 4, M = 32 channels.
// out[e,o,m] = (sum_i basis[e,o,i] * nf[U[e],i,m]) * ew[e, (o==0?0:1), m]
//
// Round-1 structure (158 us): 8 lanes per edge, each lane owns a float4 of 4
// channels; all loads/stores 16B/lane, coalesced within each 8-lane group.
// Round-3 single change: NONTEMPORAL STORES on the 409.6 MB write-only output
// stream (59% of traffic) so it does not allocate in L2 — keeps L2 free for
// the 25.6 MB node_features gather table (reused ~16x, fits 32 MB aggregate L2).
// Loads stay normal (basis rows are lane-broadcast; nt loads regressed in R2).

typedef float f4 __attribute__((ext_vector_type(4)));

__global__ __launch_bounds__(256) void equiv_mm_kernel(
    const float* __restrict__ basis,   // [E,4,4]
    const float* __restrict__ ew,      // [E,2,32]
    const float* __restrict__ nf,      // [N,4,32]
    const int*   __restrict__ U,       // [E]
    float*       __restrict__ out,     // [E,4,32]
    int E)
{
    int gid = blockIdx.x * blockDim.x + threadIdx.x;
    int e = gid >> 3;
    if (e >= E) return;
    int m0 = (gid & 7) << 2;   // channel offset: 0,4,...,28

    int u = U[e];

    // gather source-node features: rows i=0..3, stride 32 floats (=8 f4)
    const f4* xp = (const f4*)(nf + (size_t)u * 128 + m0);
    f4 x0 = xp[0];
    f4 x1 = xp[8];
    f4 x2 = xp[16];
    f4 x3 = xp[24];

    // per-edge 4x4 basis (broadcast across the 8 lanes of this edge)
    const f4* bp = (const f4*)(basis + (size_t)e * 16);
    f4 b0 = bp[0], b1 = bp[1], b2 = bp[2], b3 = bp[3];

    // radial weights: degree 0 (o=0) and degree 1 (o=1..3)
    const f4* wp = (const f4*)(ew + (size_t)e * 64 + m0);
    f4 w0 = wp[0];
    f4 w1 = wp[8];

    // write-only output stream -> nontemporal (no L2 allocate)
    f4* op = (f4*)(out + (size_t)e * 128 + m0);
    __builtin_nontemporal_store((b0.x * x0 + b0.y * x1 + b0.z * x2 + b0.w * x3) * w0, op + 0);
    __builtin_nontemporal_store((b1.x * x0 + b1.y * x1 + b1.z * x2 + b1.w * x3) * w1, op + 8);
    __builtin_nontemporal_store((b2.x * x0 + b2.y * x1 + b2.z * x2 + b2.w * x3) * w1, op + 16);
    __builtin_nontemporal_store((b3.x * x0 + b3.y * x1 + b3.z * x2 + b3.w * x3) * w1, op + 24);
}

extern "C" void kernel_launch(void* const* d_in, const int* in_sizes, int n_in,
                              void* d_out, int out_size, void* d_ws, size_t ws_size,
                              hipStream_t stream) {
    const float* basis = (const float*)d_in[0];   // [E,4,4]
    const float* ew    = (const float*)d_in[1];   // [E,2,32]
    const float* nf    = (const float*)d_in[2];   // [N,4,32]
    const int*   U     = (const int*)d_in[3];     // [E]
    float* out = (float*)d_out;

    int E = in_sizes[0] / 16;
    long long total = (long long)E * 8;           // 8 lanes per edge
    int block = 256;
    int grid = (int)((total + block - 1) / block);

    equiv_mm_kernel<<<grid, block, 0, stream>>>(basis, ew, nf, U, out, E);
}